// Round 7
// baseline (561.050 us; speedup 1.0000x reference)
//
#include <hip/hip_runtime.h>

#define NTOK 8192
#define CDIM 1024
#define HDIM 128

typedef __attribute__((ext_vector_type(8))) short short8;
typedef __attribute__((ext_vector_type(4))) float floatx4;
typedef __attribute__((ext_vector_type(4))) unsigned short ushort4v;

__device__ inline unsigned short f2bf(float f) {
    union { float f; unsigned u; } v; v.f = f;
    unsigned r = v.u + 0x7fffu + ((v.u >> 16) & 1u);
    return (unsigned short)(r >> 16);
}
__device__ inline unsigned short f2bf_fast(float f) {
    union { float f; unsigned u; } v; v.f = f;
    return (unsigned short)((v.u + 0x8000u) >> 16);
}
__device__ inline float bf2f(short s) {
    union { unsigned u; float f; } v;
    v.u = ((unsigned)(unsigned short)s) << 16;
    return v.f;
}
__device__ inline void async16(const unsigned short* g, short* l) {
    __builtin_amdgcn_global_load_lds(
        (const __attribute__((address_space(1))) unsigned*)g,
        (__attribute__((address_space(3))) unsigned*)l, 16, 0, 0);
}

// ---------------- cast fp32 -> bf16, 4 elems/thread ----------------
__global__ void cast_f32_bf16(const float* __restrict__ in,
                              unsigned short* __restrict__ out, int n4) {
    int i = blockIdx.x * blockDim.x + threadIdx.x;
    if (i < n4) {
        float4 v = ((const float4*)in)[i];
        ushort4 o;
        o.x = f2bf(v.x); o.y = f2bf(v.y); o.z = f2bf(v.z); o.w = f2bf(v.w);
        ((ushort4*)out)[i] = o;
    }
}

// ---------------- 64-tile NT GEMM (narrow N: q/k proj) ----------------
// SWZ=0: bf16 row-major out, scaled by oscale. SWZ=1: K-swizzled out.
template<int SWZ>
__global__ __launch_bounds__(256) void gemm_nt(
    const unsigned short* __restrict__ A, const unsigned short* __restrict__ W,
    const float* __restrict__ bias, unsigned short* __restrict__ out, int M, int N, int K,
    float oscale)
{
    __shared__ short As[4][64][8];
    __shared__ short Ws[4][64][8];
    const int tid = threadIdx.x;
    const int wave = tid >> 6, lane = tid & 63;
    const int lr = lane & 15, lc = lane >> 4;
    const int m0 = blockIdx.x * 64, n0 = blockIdx.y * 64;

    floatx4 acc[4] = {};
    const int srow = tid >> 2, sch = tid & 3;
    const unsigned short* Ag = A + (long)(m0 + srow) * K + sch * 8;
    const unsigned short* Wg = W + (long)(n0 + srow) * K + sch * 8;

    for (int k0 = 0; k0 < K; k0 += 32) {
        *(short8*)&As[sch][srow][0] = *(const short8*)(Ag + k0);
        *(short8*)&Ws[sch][srow][0] = *(const short8*)(Wg + k0);
        __syncthreads();
        short8 a = *(short8*)&As[lc][wave * 16 + lr][0];
#pragma unroll
        for (int s = 0; s < 4; s++) {
            short8 b = *(short8*)&Ws[lc][s * 16 + lr][0];
            acc[s] = __builtin_amdgcn_mfma_f32_16x16x32_bf16(a, b, acc[s], 0, 0, 0);
        }
        __syncthreads();
    }

#pragma unroll
    for (int s = 0; s < 4; s++) {
        int h = n0 + s * 16 + lr;
        float bv = bias[h];
        int tok0 = m0 + wave * 16 + lc * 4;
#pragma unroll
        for (int r = 0; r < 4; r++) {
            int tok = tok0 + r;
            if (SWZ)
                out[(tok >> 5) * 4096 + (h >> 3) * 256 + (tok & 31) * 8 + (h & 7)] =
                    f2bf(acc[s][r] + bv);
            else
                out[(long)tok * N + h] = f2bf((acc[s][r] + bv) * oscale);
        }
    }
}

// ---------------- 128-tile NT GEMM, global_load_lds staging ----------------
// MODE 0: f32 out row-major; MODE 2: V-swizzled bf16 out
template<int MODE>
__global__ __launch_bounds__(256) void gemm128_nt(
    const unsigned short* __restrict__ A, const unsigned short* __restrict__ W,
    const float* __restrict__ bias, void* __restrict__ out, int M, int N, int K)
{
    __shared__ short As[128][4][8]; // [row][k-chunk][8]
    __shared__ short Ws[128][4][8];
    const int tid = threadIdx.x, wave = tid >> 6, lane = tid & 63;
    const int lr = lane & 15, lc = lane >> 4;
    const int wm = (wave >> 1) * 64, wn = (wave & 1) * 64;
    const int m0 = blockIdx.x * 128, n0 = blockIdx.y * 128;

    floatx4 acc[4][4] = {};

    const int srow = lane >> 2, sch = lane & 3;
    const unsigned short* Ag0 = A + (long)(m0 + wave * 32 + srow) * K + sch * 8;
    const unsigned short* Ag1 = Ag0 + (long)16 * K;
    const unsigned short* Wg0 = W + (long)(n0 + wave * 32 + srow) * K + sch * 8;
    const unsigned short* Wg1 = Wg0 + (long)16 * K;
    short* lA0 = &As[wave * 32][0][0];
    short* lA1 = &As[wave * 32 + 16][0][0];
    short* lW0 = &Ws[wave * 32][0][0];
    short* lW1 = &Ws[wave * 32 + 16][0][0];

    for (int k0 = 0; k0 < K; k0 += 32) {
        async16(Ag0 + k0, lA0);
        async16(Ag1 + k0, lA1);
        async16(Wg0 + k0, lW0);
        async16(Wg1 + k0, lW1);
        __syncthreads();
        short8 af[4], bfg[4];
#pragma unroll
        for (int i = 0; i < 4; i++) af[i]  = *(short8*)&As[wm + i * 16 + lr][lc][0];
#pragma unroll
        for (int j = 0; j < 4; j++) bfg[j] = *(short8*)&Ws[wn + j * 16 + lr][lc][0];
#pragma unroll
        for (int i = 0; i < 4; i++)
#pragma unroll
            for (int j = 0; j < 4; j++)
                acc[i][j] = __builtin_amdgcn_mfma_f32_16x16x32_bf16(af[i], bfg[j], acc[i][j], 0, 0, 0);
        __syncthreads();
    }

#pragma unroll
    for (int i = 0; i < 4; i++) {
        int t0 = m0 + wm + i * 16 + lc * 4;
#pragma unroll
        for (int j = 0; j < 4; j++) {
            int c = n0 + wn + j * 16 + lr;
            float bv = bias[c];
            if (MODE == 0) {
                float* o = (float*)out;
#pragma unroll
                for (int r = 0; r < 4; r++) o[(long)(t0 + r) * N + c] = acc[i][j][r] + bv;
            } else {
                unsigned short* o = (unsigned short*)out;
                ushort4 pk;
                pk.x = f2bf(acc[i][j][0] + bv); pk.y = f2bf(acc[i][j][1] + bv);
                pk.z = f2bf(acc[i][j][2] + bv); pk.w = f2bf(acc[i][j][3] + bv);
                long off = (long)(c >> 8) * 2097152 + (t0 >> 5) * 8192 +
                           ((t0 & 31) >> 3) * 2048 + (c & 255) * 8 + (t0 & 7);
                *(ushort4*)&o[off] = pk;
            }
        }
    }
}

// ---------------- fused attention: partial O = exp2(q_scaled.K^T) @ V + rowsum ----------------
// grid (m-tiles=32, c-tiles=4, n-split=2); block: 4 waves, each wave 64 q-rows x 256 c.
// Software-pipelined halves: S1/P1 chains interleave with PV0's MFMA burst.
// q is pre-scaled by scale*log2e in the projection -> exp2 directly.
__global__ __launch_bounds__(256, 1) void attn_pv(
    const unsigned short* __restrict__ qb, const unsigned short* __restrict__ ksw,
    const unsigned short* __restrict__ vsw,
    unsigned short* __restrict__ Oa, unsigned short* __restrict__ Ob,
    float* __restrict__ la, float* __restrict__ lb)
{
    __shared__ short Ks[2][2][16][32][8];  // 32 KB [buf][half]
    __shared__ short Vs[2][2][4][256][8];  // 64 KB [buf][half]
    __shared__ short Ps[4][2][64][40];     // 40 KB [wave][half][m][n+pad]

    const int tid = threadIdx.x, wave = tid >> 6, lane = tid & 63;
    const int lr = lane & 15, lc = lane >> 4;
    const int m0 = blockIdx.x * 256, cblk = blockIdx.y;
    const int mw = m0 + wave * 64;
    const int nt0 = blockIdx.z * 128; // in 32-n tiles; 64 iters x 2 halves
    unsigned short* Op = blockIdx.z ? Ob : Oa;
    float* ls = blockIdx.z ? lb : la;

    // Q fragments (B-operand of S^T mfma); q pre-scaled by scale*log2e
    short8 qf[4][4];
#pragma unroll
    for (int ms = 0; ms < 4; ms++)
#pragma unroll
        for (int kk = 0; kk < 4; kk++)
            qf[ms][kk] = *(const short8*)&qb[(mw + ms * 16 + lr) * HDIM + kk * 32 + lc * 8];

    floatx4 acc[4][16] = {};
    float lsum[4] = {};

    // staging: every wave-load = 64 lanes x 16 B = 1 KB contiguous
    const unsigned short* kg[2];
    short* const klb = &Ks[0][0][0][0][0];
#pragma unroll
    for (int t = 0; t < 2; t++) kg[t] = ksw + (wave * 2 + t) * 512 + lane * 8;
    const unsigned short* vg[4];
    short* const vlb = &Vs[0][0][0][0][0];
#pragma unroll
    for (int t = 0; t < 4; t++)
        vg[t] = vsw + (long)cblk * 2097152 + (wave * 4 + t) * 512 + lane * 8;

    // prologue: stage iteration 0 (both halves) into buf 0
#pragma unroll
    for (int h = 0; h < 2; h++) {
        long nt = nt0 + h;
#pragma unroll
        for (int t = 0; t < 2; t++)
            async16(kg[t] + nt * 4096, klb + h * 4096 + (wave * 2 + t) * 512);
#pragma unroll
        for (int t = 0; t < 4; t++)
            async16(vg[t] + nt * 8192, vlb + h * 8192 + (wave * 4 + t) * 512);
    }

    for (int it = 0; it < 64; ++it) {
        const int buf = it & 1;
        __syncthreads(); // drains vmem -> buf ready; all waves done with buf^1
        if (it + 1 < 64) {
#pragma unroll
            for (int h = 0; h < 2; h++) {
                long nt = nt0 + 2 * (it + 1) + h;
#pragma unroll
                for (int t = 0; t < 2; t++)
                    async16(kg[t] + nt * 4096,
                            klb + (buf ^ 1) * 8192 + h * 4096 + (wave * 2 + t) * 512);
#pragma unroll
                for (int t = 0; t < 4; t++)
                    async16(vg[t] + nt * 8192,
                            vlb + (buf ^ 1) * 16384 + h * 8192 + (wave * 4 + t) * 512);
            }
        }

        // ---- S0: S^T for half 0 (32 MFMA) ----
        floatx4 st0[4][2] = {};
#pragma unroll
        for (int kk = 0; kk < 4; kk++) {
            short8 kf0 = *(short8*)&Ks[buf][0][kk * 4 + lc][lr][0];
            short8 kf1 = *(short8*)&Ks[buf][0][kk * 4 + lc][16 + lr][0];
#pragma unroll
            for (int ms = 0; ms < 4; ms++) {
                st0[ms][0] = __builtin_amdgcn_mfma_f32_16x16x32_bf16(kf0, qf[ms][kk], st0[ms][0], 0, 0, 0);
                st0[ms][1] = __builtin_amdgcn_mfma_f32_16x16x32_bf16(kf1, qf[ms][kk], st0[ms][1], 0, 0, 0);
            }
        }
        // ---- P0 = exp2(st0) -> Ps[.][0] ----
#pragma unroll
        for (int ms = 0; ms < 4; ms++)
#pragma unroll
            for (int sub = 0; sub < 2; sub++) {
                ushort4v pk;
#pragma unroll
                for (int r = 0; r < 4; r++) {
                    float p = __builtin_amdgcn_exp2f(st0[ms][sub][r]);
                    lsum[ms] += p;
                    pk[r] = f2bf_fast(p);
                }
                *(ushort4v*)&Ps[wave][0][ms * 16 + lr][sub * 16 + lc * 4] = pk;
            }

        // ---- S1: independent chain (32 MFMA), hides P0 write->read latency ----
        floatx4 st1[4][2] = {};
#pragma unroll
        for (int kk = 0; kk < 4; kk++) {
            short8 kf0 = *(short8*)&Ks[buf][1][kk * 4 + lc][lr][0];
            short8 kf1 = *(short8*)&Ks[buf][1][kk * 4 + lc][16 + lr][0];
#pragma unroll
            for (int ms = 0; ms < 4; ms++) {
                st1[ms][0] = __builtin_amdgcn_mfma_f32_16x16x32_bf16(kf0, qf[ms][kk], st1[ms][0], 0, 0, 0);
                st1[ms][1] = __builtin_amdgcn_mfma_f32_16x16x32_bf16(kf1, qf[ms][kk], st1[ms][1], 0, 0, 0);
            }
        }
        // ---- ap0 read; P1 = exp2(st1) -> Ps[.][1] (VALU overlaps PV0 MFMAs below) ----
        short8 ap0[4];
#pragma unroll
        for (int ms = 0; ms < 4; ms++) ap0[ms] = *(short8*)&Ps[wave][0][ms * 16 + lr][lc * 8];
#pragma unroll
        for (int ms = 0; ms < 4; ms++)
#pragma unroll
            for (int sub = 0; sub < 2; sub++) {
                ushort4v pk;
#pragma unroll
                for (int r = 0; r < 4; r++) {
                    float p = __builtin_amdgcn_exp2f(st1[ms][sub][r]);
                    lsum[ms] += p;
                    pk[r] = f2bf_fast(p);
                }
                *(ushort4v*)&Ps[wave][1][ms * 16 + lr][sub * 16 + lc * 4] = pk;
            }

        // ---- PV0: O += P0 @ V0 (64 MFMA) ----
#pragma unroll
        for (int csh = 0; csh < 2; csh++) {
            short8 bv[8];
#pragma unroll
            for (int cs = 0; cs < 8; cs++)
                bv[cs] = *(short8*)&Vs[buf][0][lc][(csh * 8 + cs) * 16 + lr][0];
#pragma unroll
            for (int ms = 0; ms < 4; ms++)
#pragma unroll
                for (int cs = 0; cs < 8; cs++)
                    acc[ms][csh * 8 + cs] =
                        __builtin_amdgcn_mfma_f32_16x16x32_bf16(ap0[ms], bv[cs], acc[ms][csh * 8 + cs], 0, 0, 0);
        }
        // ---- PV1: O += P1 @ V1 (64 MFMA) ----
        short8 ap1[4];
#pragma unroll
        for (int ms = 0; ms < 4; ms++) ap1[ms] = *(short8*)&Ps[wave][1][ms * 16 + lr][lc * 8];
#pragma unroll
        for (int csh = 0; csh < 2; csh++) {
            short8 bv[8];
#pragma unroll
            for (int cs = 0; cs < 8; cs++)
                bv[cs] = *(short8*)&Vs[buf][1][lc][(csh * 8 + cs) * 16 + lr][0];
#pragma unroll
            for (int ms = 0; ms < 4; ms++)
#pragma unroll
                for (int cs = 0; cs < 8; cs++)
                    acc[ms][csh * 8 + cs] =
                        __builtin_amdgcn_mfma_f32_16x16x32_bf16(ap1[ms], bv[cs], acc[ms][csh * 8 + cs], 0, 0, 0);
        }
    }

    // unnormalized partial O
#pragma unroll
    for (int ms = 0; ms < 4; ms++)
#pragma unroll
        for (int cs = 0; cs < 16; cs++) {
            int c = cblk * 256 + cs * 16 + lr;
#pragma unroll
            for (int r = 0; r < 4; r++)
                Op[(long)(mw + ms * 16 + lc * 4 + r) * CDIM + c] = f2bf(acc[ms][cs][r]);
        }
    // partial row sums (q-row = ms*16+lr; reduce over lc lanes)
    if (blockIdx.y == 0) {
#pragma unroll
        for (int ms = 0; ms < 4; ms++) {
            lsum[ms] += __shfl_xor(lsum[ms], 16);
            lsum[ms] += __shfl_xor(lsum[ms], 32);
        }
        if (lc == 0) {
#pragma unroll
            for (int ms = 0; ms < 4; ms++) ls[mw + ms * 16 + lr] = lsum[ms];
        }
    }
}

// ---------------- combine: attn = (Oa + Ob) / (la + lb), in place over Ob ----------------
__global__ __launch_bounds__(256) void combine_attn(
    const unsigned short* __restrict__ Oa, unsigned short* __restrict__ Ob,
    const float* __restrict__ la, const float* __restrict__ lb)
{
    int i = blockIdx.x * blockDim.x + threadIdx.x; // one per 8 elems
    int row = i >> 7;                              // CDIM/8 = 128
    float inv = 1.0f / (la[row] + lb[row]);
    short8 a = ((const short8*)Oa)[i];
    short8 b = ((const short8*)Ob)[i];
    short8 o;
#pragma unroll
    for (int e = 0; e < 8; e++) o[e] = (short)f2bf((bf2f(a[e]) + bf2f(b[e])) * inv);
    ((short8*)Ob)[i] = o;
}

extern "C" void kernel_launch(void* const* d_in, const int* in_sizes, int n_in,
                              void* d_out, int out_size, void* d_ws, size_t ws_size,
                              hipStream_t stream) {
    const float* x  = (const float*)d_in[0];
    const float* Wq = (const float*)d_in[1];
    const float* bq = (const float*)d_in[2];
    const float* Wk = (const float*)d_in[3];
    const float* bk = (const float*)d_in[4];
    const float* Wv = (const float*)d_in[5];
    const float* bv = (const float*)d_in[6];
    const float* Wo = (const float*)d_in[7];
    const float* bo = (const float*)d_in[8];

    char* ws = (char*)d_ws;
    unsigned short* x_bf   = (unsigned short*)(ws + 0);          // 16 MB (reused as Oa)
    unsigned short* wq_bf  = (unsigned short*)(ws + 16777216);   // 256 KB
    unsigned short* wk_bf  = (unsigned short*)(ws + 17039360);   // 256 KB
    unsigned short* wv_bf  = (unsigned short*)(ws + 17301504);   // 2 MB
    unsigned short* wo_bf  = (unsigned short*)(ws + 19398656);   // 2 MB
    unsigned short* q_bf   = (unsigned short*)(ws + 21495808);   // 2 MB
    unsigned short* k_swz  = (unsigned short*)(ws + 23592960);   // 2 MB (K swizzled)
    unsigned short* v_swz  = (unsigned short*)(ws + 25690112);   // 16 MB (V swizzled)
    unsigned short* attn_bf= (unsigned short*)(ws + 42467328);   // 16 MB (Ob, combined in place)
    float* lsum_a          = (float*)(ws + 59244544);            // 32 KB
    float* lsum_b          = (float*)(ws + 59277312);            // 32 KB

    const float cexp = (float)(0.08838834764831845 * 1.4426950408889634); // scale*log2e

    // casts to bf16
    cast_f32_bf16<<<8192, 256, 0, stream>>>(x,  x_bf,  2097152);
    cast_f32_bf16<<<128,  256, 0, stream>>>(Wq, wq_bf, 32768);
    cast_f32_bf16<<<128,  256, 0, stream>>>(Wk, wk_bf, 32768);
    cast_f32_bf16<<<1024, 256, 0, stream>>>(Wv, wv_bf, 262144);
    cast_f32_bf16<<<1024, 256, 0, stream>>>(Wo, wo_bf, 262144);

    // projections (q pre-scaled by scale*log2e)
    gemm_nt<0><<<dim3(128, 2), 256, 0, stream>>>(x_bf, wq_bf, bq, q_bf, NTOK, HDIM, CDIM, cexp);
    gemm_nt<1><<<dim3(128, 2), 256, 0, stream>>>(x_bf, wk_bf, bk, k_swz, NTOK, HDIM, CDIM, 1.0f);
    gemm128_nt<2><<<dim3(64, 8), 256, 0, stream>>>(x_bf, wv_bf, bv, v_swz, NTOK, CDIM, CDIM);

    // fused attention (split-n over gridDim.z); Oa overlays dead x_bf
    attn_pv<<<dim3(32, 4, 2), 256, 0, stream>>>(q_bf, k_swz, v_swz,
                                                x_bf, attn_bf, lsum_a, lsum_b);
    combine_attn<<<4096, 256, 0, stream>>>(x_bf, attn_bf, lsum_a, lsum_b);

    // output projection (fp32 out)
    gemm128_nt<0><<<dim3(64, 8), 256, 0, stream>>>(attn_bf, wo_bf, bo, d_out, NTOK, CDIM, CDIM);
}